// Round 1
// baseline (1642.215 us; speedup 1.0000x reference)
//
#include <hip/hip_runtime.h>
#include <math.h>

// ---------------------------------------------------------------------------
// ProteinInteractionPredictor: MLP(meta_a), MLP(meta_b), GCNx2(x_a), GCNx2(x_b)
// -> concat [N,512] -> relu(fcc) -> sigmoid(out)
//
// GCN refactor: h = X@W; hs = h * dinv[row]  (done in GEMM epilogue)
//   out[v] = relu( dinv[v] * ( hs[v] + sum_{s->v} hs[s] ) + b )
// CSR (by dst) built once per graph, reused for both layers.
// ---------------------------------------------------------------------------

#define BM 64
#define BK 32

__launch_bounds__(256)
__global__ void gemm128(const float* __restrict__ A, int lda,
                        const float* __restrict__ W,      // [K,128] row-major
                        const float* __restrict__ bias,   // [128] or null
                        const float* __restrict__ rowscale, // [M] or null
                        float* __restrict__ C, int ldc, int col_off,
                        int M, int K, int do_relu) {
  __shared__ float As[BM][BK + 4];   // +4 pad keeps float4 alignment, breaks bank cycles
  __shared__ float Ws[BK][128];
  const int tid = threadIdx.x;
  const int m0 = blockIdx.x * BM;
  const int rb = (tid >> 5) * 8;   // 8 row-groups of 8
  const int cb = (tid & 31) * 4;   // 32 col-groups of 4

  float acc[8][4];
#pragma unroll
  for (int i = 0; i < 8; i++)
#pragma unroll
    for (int j = 0; j < 4; j++) acc[i][j] = 0.f;

  for (int k0 = 0; k0 < K; k0 += BK) {
    __syncthreads();
    // A tile: 64 rows x 32 k  (2 passes of 32 rows, float4 per thread)
#pragma unroll
    for (int p = 0; p < 2; p++) {
      int r = p * 32 + (tid >> 3);
      int kq = (tid & 7) * 4;
      float4 v = make_float4(0.f, 0.f, 0.f, 0.f);
      int row = m0 + r;
      if (row < M) v = *(const float4*)(A + (size_t)row * lda + k0 + kq);
      *(float4*)(&As[r][kq]) = v;
    }
    // W tile: 32 k x 128 cols (4 passes of 8 rows)
#pragma unroll
    for (int p = 0; p < 4; p++) {
      int r = p * 8 + (tid >> 5);
      int c4 = (tid & 31) * 4;
      *(float4*)(&Ws[r][c4]) = *(const float4*)(W + (size_t)(k0 + r) * 128 + c4);
    }
    __syncthreads();
#pragma unroll
    for (int kk = 0; kk < BK; kk++) {
      float4 b = *(const float4*)(&Ws[kk][cb]);
      float a[8];
#pragma unroll
      for (int i = 0; i < 8; i++) a[i] = As[rb + i][kk];
#pragma unroll
      for (int i = 0; i < 8; i++) {
        acc[i][0] += a[i] * b.x;
        acc[i][1] += a[i] * b.y;
        acc[i][2] += a[i] * b.z;
        acc[i][3] += a[i] * b.w;
      }
    }
  }

  float4 bi = make_float4(0.f, 0.f, 0.f, 0.f);
  if (bias) bi = *(const float4*)(bias + cb);
#pragma unroll
  for (int i = 0; i < 8; i++) {
    int row = m0 + rb + i;
    if (row < M) {
      float rs = rowscale ? rowscale[row] : 1.0f;
      float4 o;
      o.x = acc[i][0] * rs + bi.x;
      o.y = acc[i][1] * rs + bi.y;
      o.z = acc[i][2] * rs + bi.z;
      o.w = acc[i][3] * rs + bi.w;
      if (do_relu) {
        o.x = fmaxf(o.x, 0.f); o.y = fmaxf(o.y, 0.f);
        o.z = fmaxf(o.z, 0.f); o.w = fmaxf(o.w, 0.f);
      }
      *(float4*)(C + (size_t)row * ldc + col_off + cb) = o;
    }
  }
}

__global__ void deg_count(const int* __restrict__ dst, int E, int* __restrict__ deg) {
  int i = blockIdx.x * blockDim.x + threadIdx.x;
  if (i < E) atomicAdd(&deg[dst[i]], 1);
}

__global__ void dinv_kernel(const int* __restrict__ deg, float* __restrict__ dinv, int n) {
  int i = blockIdx.x * blockDim.x + threadIdx.x;
  if (i < n) dinv[i] = rsqrtf((float)(deg[i] + 1));  // +1 self-loop
}

// single-block scan: row_ptr[0]=0; row_ptr[i+1]=sum(deg[0..i]); chunks of 1024
__launch_bounds__(256)
__global__ void scan_deg(const int* __restrict__ deg, int* __restrict__ row_ptr, int n) {
  __shared__ int sm[256];
  __shared__ int carry;
  int tid = threadIdx.x;
  if (tid == 0) { carry = 0; row_ptr[0] = 0; }
  __syncthreads();
  for (int base = 0; base < n; base += 1024) {
    int i0 = base + tid * 4;
    int4 v = make_int4(0, 0, 0, 0);
    if (i0 + 3 < n) v = *(const int4*)(deg + i0);
    else {
      if (i0 < n) v.x = deg[i0];
      if (i0 + 1 < n) v.y = deg[i0 + 1];
      if (i0 + 2 < n) v.z = deg[i0 + 2];
    }
    int s1 = v.x, s2 = s1 + v.y, s3 = s2 + v.z, s4 = s3 + v.w;
    int val = s4;
    sm[tid] = val;
    __syncthreads();
    for (int off = 1; off < 256; off <<= 1) {
      int t = (tid >= off) ? sm[tid - off] : 0;
      __syncthreads();
      val += t;
      sm[tid] = val;
      __syncthreads();
    }
    int excl = val - s4 + carry;
    if (i0 < n)     row_ptr[i0 + 1] = excl + s1;
    if (i0 + 1 < n) row_ptr[i0 + 2] = excl + s2;
    if (i0 + 2 < n) row_ptr[i0 + 3] = excl + s3;
    if (i0 + 3 < n) row_ptr[i0 + 4] = excl + s4;
    __syncthreads();
    if (tid == 255) carry += sm[255];
    __syncthreads();
  }
}

__global__ void fill_csr(const int* __restrict__ src, const int* __restrict__ dst, int E,
                         const int* __restrict__ row_ptr, int* __restrict__ cursor,
                         int* __restrict__ csr) {
  int i = blockIdx.x * blockDim.x + threadIdx.x;
  if (i < E) {
    int d = dst[i];
    int pos = atomicAdd(&cursor[d], 1);
    csr[row_ptr[d] + pos] = src[i];
  }
}

// one wave per node; thread t owns cols {2t, 2t+1}
__launch_bounds__(64)
__global__ void gather_kernel(const float2* __restrict__ hs, const int* __restrict__ csr,
                              const int* __restrict__ row_ptr, const float* __restrict__ dinv,
                              const float* __restrict__ bias, float* __restrict__ out,
                              int ldc, int col_off) {
  int v = blockIdx.x;
  int t = threadIdx.x;
  int beg = row_ptr[v], end = row_ptr[v + 1];
  float2 acc = hs[(size_t)v * 64 + t];  // self-loop term
  int e = beg;
  int s = (e < end) ? csr[e] : 0;
  while (e < end) {
    int s_cur = s;
    if (e + 1 < end) s = csr[e + 1];
    float2 m = hs[(size_t)s_cur * 64 + t];
    acc.x += m.x;
    acc.y += m.y;
    e++;
  }
  float dv = dinv[v];
  float2 bi = ((const float2*)bias)[t];
  float ox = fmaxf(acc.x * dv + bi.x, 0.f);
  float oy = fmaxf(acc.y * dv + bi.y, 0.f);
  *(float2*)(out + (size_t)v * ldc + col_off + 2 * t) = make_float2(ox, oy);
}

// final: y[v] = sigmoid(dot(f[v,:128], out_W) + out_b); one wave per row
__launch_bounds__(256)
__global__ void final_out(const float* __restrict__ f, const float* __restrict__ outW,
                          const float* __restrict__ outb, float* __restrict__ y, int n) {
  int gw = (blockIdx.x * 256 + threadIdx.x) >> 6;
  int lane = threadIdx.x & 63;
  if (gw >= n) return;
  const float2* fr = (const float2*)(f + (size_t)gw * 128);
  const float2* w2 = (const float2*)outW;
  float2 a = fr[lane], b = w2[lane];
  float p = a.x * b.x + a.y * b.y;
#pragma unroll
  for (int off = 32; off > 0; off >>= 1) p += __shfl_down(p, off, 64);
  if (lane == 0) y[gw] = 1.f / (1.f + expf(-(p + outb[0])));
}

extern "C" void kernel_launch(void* const* d_in, const int* in_sizes, int n_in,
                              void* d_out, int out_size, void* d_ws, size_t ws_size,
                              hipStream_t stream) {
  const float* meta_a = (const float*)d_in[0];
  const float* meta_b = (const float*)d_in[1];
  const float* x_a    = (const float*)d_in[2];
  const float* x_b    = (const float*)d_in[3];
  const int*   ei_a   = (const int*)d_in[4];
  const int*   ei_b   = (const int*)d_in[5];
  const float* fc1_W = (const float*)d_in[6];
  const float* fc1_b = (const float*)d_in[7];
  const float* fc2_W = (const float*)d_in[8];
  const float* fc2_b = (const float*)d_in[9];
  const float* gcn1_W = (const float*)d_in[10];
  const float* gcn1_b = (const float*)d_in[11];
  const float* gcn2_W = (const float*)d_in[12];
  const float* gcn2_b = (const float*)d_in[13];
  const float* fcc_W = (const float*)d_in[14];
  const float* fcc_b = (const float*)d_in[15];
  const float* out_W = (const float*)d_in[16];
  const float* out_b = (const float*)d_in[17];
  float* y = (float*)d_out;

  const int N = in_sizes[0] / 512;
  const int E = in_sizes[4] / 2;

  // workspace layout (all fp32/int32, 4B elems)
  float* ws = (float*)d_ws;
  float* combined = ws;                    // N*512
  float* bufA = combined + (size_t)N * 512; // N*128
  float* bufB = bufA + (size_t)N * 128;     // N*128
  int* deg = (int*)(bufB + (size_t)N * 128); // N
  int* cursor = deg + N;                    // N
  int* row_ptr = cursor + N;                // N+1
  float* dinv = (float*)(row_ptr + N + 1);  // N
  int* csr = (int*)(dinv + N);              // E

  const int gemm_grid = (N + BM - 1) / BM;
  const int eg = (E + 255) / 256;
  const int ng = (N + 255) / 256;

  // ---------------- MLP branches ----------------
  gemm128<<<gemm_grid, 256, 0, stream>>>(meta_a, 512, fc1_W, fc1_b, nullptr, bufA, 128, 0, N, 512, 1);
  gemm128<<<gemm_grid, 256, 0, stream>>>(bufA, 128, fc2_W, fc2_b, nullptr, combined, 512, 0, N, 128, 1);
  gemm128<<<gemm_grid, 256, 0, stream>>>(meta_b, 512, fc1_W, fc1_b, nullptr, bufA, 128, 0, N, 512, 1);
  gemm128<<<gemm_grid, 256, 0, stream>>>(bufA, 128, fc2_W, fc2_b, nullptr, combined, 512, 128, N, 128, 1);

  // ---------------- GCN branch A ----------------
  hipMemsetAsync(deg, 0, (size_t)2 * N * 4, stream);  // deg + cursor
  deg_count<<<eg, 256, 0, stream>>>(ei_a + E, E, deg);
  dinv_kernel<<<ng, 256, 0, stream>>>(deg, dinv, N);
  scan_deg<<<1, 256, 0, stream>>>(deg, row_ptr, N);
  fill_csr<<<eg, 256, 0, stream>>>(ei_a, ei_a + E, E, row_ptr, cursor, csr);

  gemm128<<<gemm_grid, 256, 0, stream>>>(x_a, 256, gcn1_W, nullptr, dinv, bufB, 128, 0, N, 256, 0);
  gather_kernel<<<N, 64, 0, stream>>>((const float2*)bufB, csr, row_ptr, dinv, gcn1_b, bufA, 128, 0);
  gemm128<<<gemm_grid, 256, 0, stream>>>(bufA, 128, gcn2_W, nullptr, dinv, bufB, 128, 0, N, 128, 0);
  gather_kernel<<<N, 64, 0, stream>>>((const float2*)bufB, csr, row_ptr, dinv, gcn2_b, combined, 512, 256);

  // ---------------- GCN branch B ----------------
  hipMemsetAsync(deg, 0, (size_t)2 * N * 4, stream);
  deg_count<<<eg, 256, 0, stream>>>(ei_b + E, E, deg);
  dinv_kernel<<<ng, 256, 0, stream>>>(deg, dinv, N);
  scan_deg<<<1, 256, 0, stream>>>(deg, row_ptr, N);
  fill_csr<<<eg, 256, 0, stream>>>(ei_b, ei_b + E, E, row_ptr, cursor, csr);

  gemm128<<<gemm_grid, 256, 0, stream>>>(x_b, 256, gcn1_W, nullptr, dinv, bufB, 128, 0, N, 256, 0);
  gather_kernel<<<N, 64, 0, stream>>>((const float2*)bufB, csr, row_ptr, dinv, gcn1_b, bufA, 128, 0);
  gemm128<<<gemm_grid, 256, 0, stream>>>(bufA, 128, gcn2_W, nullptr, dinv, bufB, 128, 0, N, 128, 0);
  gather_kernel<<<N, 64, 0, stream>>>((const float2*)bufB, csr, row_ptr, dinv, gcn2_b, combined, 512, 384);

  // ---------------- head ----------------
  gemm128<<<gemm_grid, 256, 0, stream>>>(combined, 512, fcc_W, fcc_b, nullptr, bufA, 128, 0, N, 512, 1);
  final_out<<<(N + 3) / 4, 256, 0, stream>>>(bufA, out_W, out_b, y, N);
}

// Round 2
// 1180.983 us; speedup vs baseline: 1.3905x; 1.3905x over previous
//
#include <hip/hip_runtime.h>
#include <math.h>

// ---------------------------------------------------------------------------
// bf16-MFMA version.
// GEMMs: D = A@W (+bias)(*rowscale[row]) via v_mfma_f32_16x16x32_bf16.
//   A [M,K] bf16 (or fp32 converted in-register), Wt [128,K] bf16 (pre-transposed).
//   Fragment layouts (guide §3, m89-verified):
//     A: lane holds A[m=lane&15][k=(lane>>4)*8 + j], j=0..7
//     B: lane holds B[k=(lane>>4)*8 + j][n=lane&15]
//     C/D: col=lane&15, row=(lane>>4)*4 + reg
// GCN: hs = (X@W)*dinv[row]; out[v] = relu(dinv[v]*(hs[v]+sum_in hs[s]) + b)
// CSR built once per graph (merged A+B launches), activations bf16 throughout.
// ---------------------------------------------------------------------------

typedef __attribute__((ext_vector_type(8))) short bf16x8;
typedef __attribute__((ext_vector_type(4))) float f32x4;

static __device__ __forceinline__ unsigned short f2bf(float f) {
  unsigned u = __float_as_uint(f);
  unsigned r = u + 0x7fffu + ((u >> 16) & 1u);   // RNE
  return (unsigned short)(r >> 16);
}
static __device__ __forceinline__ float bf2f(unsigned short h) {
  return __uint_as_float(((unsigned)h) << 16);
}

#define GM 128  // rows per block (4 waves x 32 rows)

__launch_bounds__(256)
__global__ void gemm_mfma(const void* __restrict__ Av, int lda, int a_fp32,
                          const unsigned short* __restrict__ Wt,  // [128,K] bf16
                          const float* __restrict__ bias,         // [128] or null
                          const float* __restrict__ rowscale,     // [M] or null
                          unsigned short* __restrict__ Cb,        // bf16 out or null
                          float* __restrict__ Cf,                 // fp32 out or null
                          int ldc, int col_off,
                          int M, int K, int do_relu) {
  const int tid = threadIdx.x;
  const int wave = tid >> 6;
  const int lane = tid & 63;
  const int quad = lane >> 4;
  const int lr = lane & 15;
  const int m0 = blockIdx.x * GM + wave * 32;  // this wave's 32 rows

  f32x4 acc[2][8];
#pragma unroll
  for (int r = 0; r < 2; r++)
#pragma unroll
    for (int c = 0; c < 8; c++) acc[r][c] = (f32x4){0.f, 0.f, 0.f, 0.f};

  // clamped row indices for the two A fragments
  int arow0 = m0 + lr;        if (arow0 > M - 1) arow0 = M - 1;
  int arow1 = m0 + 16 + lr;   if (arow1 > M - 1) arow1 = M - 1;

  for (int k0 = 0; k0 < K; k0 += 32) {
    const int kq = k0 + quad * 8;
    bf16x8 a[2];
    if (a_fp32) {
      const float* a0 = (const float*)Av + (size_t)arow0 * lda + kq;
      const float* a1 = (const float*)Av + (size_t)arow1 * lda + kq;
      float4 l0 = *(const float4*)a0, h0 = *(const float4*)(a0 + 4);
      float4 l1 = *(const float4*)a1, h1 = *(const float4*)(a1 + 4);
      a[0][0] = (short)f2bf(l0.x); a[0][1] = (short)f2bf(l0.y);
      a[0][2] = (short)f2bf(l0.z); a[0][3] = (short)f2bf(l0.w);
      a[0][4] = (short)f2bf(h0.x); a[0][5] = (short)f2bf(h0.y);
      a[0][6] = (short)f2bf(h0.z); a[0][7] = (short)f2bf(h0.w);
      a[1][0] = (short)f2bf(l1.x); a[1][1] = (short)f2bf(l1.y);
      a[1][2] = (short)f2bf(l1.z); a[1][3] = (short)f2bf(l1.w);
      a[1][4] = (short)f2bf(h1.x); a[1][5] = (short)f2bf(h1.y);
      a[1][6] = (short)f2bf(h1.z); a[1][7] = (short)f2bf(h1.w);
    } else {
      a[0] = *(const bf16x8*)((const unsigned short*)Av + (size_t)arow0 * lda + kq);
      a[1] = *(const bf16x8*)((const unsigned short*)Av + (size_t)arow1 * lda + kq);
    }
#pragma unroll
    for (int c = 0; c < 8; c++) {
      bf16x8 b = *(const bf16x8*)(Wt + (size_t)(c * 16 + lr) * K + kq);
      acc[0][c] = __builtin_amdgcn_mfma_f32_16x16x32_bf16(a[0], b, acc[0][c], 0, 0, 0);
      acc[1][c] = __builtin_amdgcn_mfma_f32_16x16x32_bf16(a[1], b, acc[1][c], 0, 0, 0);
    }
  }

  // epilogue
#pragma unroll
  for (int r = 0; r < 2; r++) {
    const int rbase = m0 + r * 16 + quad * 4;
    float rs[4];
#pragma unroll
    for (int i = 0; i < 4; i++) {
      int row = rbase + i;
      rs[i] = (rowscale && row < M) ? rowscale[row] : 1.0f;
    }
#pragma unroll
    for (int c = 0; c < 8; c++) {
      const int col = col_off + c * 16 + lr;
      const float bi = bias ? bias[c * 16 + lr] : 0.f;
#pragma unroll
      for (int i = 0; i < 4; i++) {
        int row = rbase + i;
        if (row < M) {
          float v = acc[r][c][i] * rs[i] + bi;
          if (do_relu) v = fmaxf(v, 0.f);
          if (Cb) Cb[(size_t)row * ldc + col] = f2bf(v);
          else    Cf[(size_t)row * ldc + col] = v;
        }
      }
    }
  }
}

// transpose+convert the 5 weight matrices [K,128] fp32 -> [128,K] bf16
__global__ void prep_w(const float* __restrict__ fc1, const float* __restrict__ fc2,
                       const float* __restrict__ g1, const float* __restrict__ g2,
                       const float* __restrict__ fcc, unsigned short* __restrict__ wt) {
  int i = blockIdx.x * 256 + threadIdx.x;
  const float* src[5] = {fc1, fc2, g1, g2, fcc};
  const int Ks[5] = {512, 128, 256, 128, 512};
  int off = 0;
#pragma unroll
  for (int w = 0; w < 5; w++) {
    int K = Ks[w];
    if (i < K * 128) {
      int k = i >> 7, c = i & 127;
      wt[off + c * K + k] = f2bf(src[w][i]);
    }
    off += K * 128;
  }
}

// --- CSR build, both graphs in one launch each ---
__global__ void deg_count2(const int* __restrict__ eiA, const int* __restrict__ eiB,
                           int E, int N, int* __restrict__ deg) {
  int i = blockIdx.x * blockDim.x + threadIdx.x;
  if (i < 2 * E) {
    int g = i >= E;
    int li = g ? i - E : i;
    int d = g ? eiB[E + li] : eiA[E + li];
    atomicAdd(&deg[g * N + d], 1);
  }
}

__global__ void dinv2(const int* __restrict__ deg, float* __restrict__ dinv, int n2) {
  int i = blockIdx.x * blockDim.x + threadIdx.x;
  if (i < n2) dinv[i] = rsqrtf((float)(deg[i] + 1));
}

// 2 blocks: block g scans deg[g*N..] -> rp[g*(N+1)..]
__launch_bounds__(256)
__global__ void scan_deg2(const int* __restrict__ deg_all, int* __restrict__ rp_all, int n) {
  const int g = blockIdx.x;
  const int* deg = deg_all + g * n;
  int* row_ptr = rp_all + g * (n + 1);
  __shared__ int sm[256];
  __shared__ int carry;
  int tid = threadIdx.x;
  if (tid == 0) { carry = 0; row_ptr[0] = 0; }
  __syncthreads();
  for (int base = 0; base < n; base += 1024) {
    int i0 = base + tid * 4;
    int4 v = make_int4(0, 0, 0, 0);
    if (i0 + 3 < n) v = *(const int4*)(deg + i0);
    else {
      if (i0 < n) v.x = deg[i0];
      if (i0 + 1 < n) v.y = deg[i0 + 1];
      if (i0 + 2 < n) v.z = deg[i0 + 2];
    }
    int s1 = v.x, s2 = s1 + v.y, s3 = s2 + v.z, s4 = s3 + v.w;
    int val = s4;
    sm[tid] = val;
    __syncthreads();
    for (int off = 1; off < 256; off <<= 1) {
      int t = (tid >= off) ? sm[tid - off] : 0;
      __syncthreads();
      val += t;
      sm[tid] = val;
      __syncthreads();
    }
    int excl = val - s4 + carry;
    if (i0 < n)     row_ptr[i0 + 1] = excl + s1;
    if (i0 + 1 < n) row_ptr[i0 + 2] = excl + s2;
    if (i0 + 2 < n) row_ptr[i0 + 3] = excl + s3;
    if (i0 + 3 < n) row_ptr[i0 + 4] = excl + s4;
    __syncthreads();
    if (tid == 255) carry += sm[255];
    __syncthreads();
  }
}

__global__ void fill_csr2(const int* __restrict__ eiA, const int* __restrict__ eiB,
                          int E, int N, const int* __restrict__ rp_all,
                          int* __restrict__ cursor, int* __restrict__ csrA,
                          int* __restrict__ csrB) {
  int i = blockIdx.x * blockDim.x + threadIdx.x;
  if (i < 2 * E) {
    int g = i >= E;
    int li = g ? i - E : i;
    const int* ei = g ? eiB : eiA;
    int s = ei[li], d = ei[E + li];
    int pos = atomicAdd(&cursor[g * N + d], 1);
    int* csr = g ? csrB : csrA;
    csr[rp_all[g * (N + 1) + d] + pos] = s;
  }
}

// gather for both graphs: one wave per node, lane t owns cols {2t,2t+1} (bf16 pair)
__launch_bounds__(256)
__global__ void gather2(const unsigned short* __restrict__ hsA,
                        const unsigned short* __restrict__ hsB,
                        const int* __restrict__ csrA, const int* __restrict__ csrB,
                        const int* __restrict__ rp_all, const float* __restrict__ dinv,
                        const float* __restrict__ bias,
                        unsigned short* __restrict__ outA, unsigned short* __restrict__ outB,
                        int ldA, int coA, int ldB, int coB, int N) {
  int widx = (blockIdx.x * 256 + threadIdx.x) >> 6;
  if (widx >= 2 * N) return;
  int g = widx >= N;
  int v = g ? widx - N : widx;
  const unsigned short* hs = g ? hsB : hsA;
  const int* csr = g ? csrB : csrA;
  const int* rp = rp_all + g * (N + 1);
  unsigned short* out = g ? outB : outA;
  const int ldc = g ? ldB : ldA;
  const int co = g ? coB : coA;
  const int t = threadIdx.x & 63;

  unsigned self = *(const unsigned*)(hs + (size_t)v * 128 + 2 * t);
  float ax = bf2f((unsigned short)(self & 0xffff));
  float ay = bf2f((unsigned short)(self >> 16));

  int e = rp[v], end = rp[v + 1];
  // 4-wide unroll: indices are wave-uniform (scalar loads), 4 row loads in flight
  for (; e + 4 <= end; e += 4) {
    int s0 = csr[e], s1 = csr[e + 1], s2 = csr[e + 2], s3 = csr[e + 3];
    unsigned m0 = *(const unsigned*)(hs + (size_t)s0 * 128 + 2 * t);
    unsigned m1 = *(const unsigned*)(hs + (size_t)s1 * 128 + 2 * t);
    unsigned m2 = *(const unsigned*)(hs + (size_t)s2 * 128 + 2 * t);
    unsigned m3 = *(const unsigned*)(hs + (size_t)s3 * 128 + 2 * t);
    ax += bf2f((unsigned short)(m0 & 0xffff)) + bf2f((unsigned short)(m1 & 0xffff)) +
          bf2f((unsigned short)(m2 & 0xffff)) + bf2f((unsigned short)(m3 & 0xffff));
    ay += bf2f((unsigned short)(m0 >> 16)) + bf2f((unsigned short)(m1 >> 16)) +
          bf2f((unsigned short)(m2 >> 16)) + bf2f((unsigned short)(m3 >> 16));
  }
  for (; e < end; e++) {
    int s = csr[e];
    unsigned m = *(const unsigned*)(hs + (size_t)s * 128 + 2 * t);
    ax += bf2f((unsigned short)(m & 0xffff));
    ay += bf2f((unsigned short)(m >> 16));
  }

  float dv = dinv[g * N + v];
  float2 bi = ((const float2*)bias)[t];
  float ox = fmaxf(ax * dv + bi.x, 0.f);
  float oy = fmaxf(ay * dv + bi.y, 0.f);
  unsigned packed = (unsigned)f2bf(ox) | ((unsigned)f2bf(oy) << 16);
  *(unsigned*)(out + (size_t)v * ldc + co + 2 * t) = packed;
}

// y[v] = sigmoid(dot(f[v,:128], out_W) + out_b); one wave per row
__launch_bounds__(256)
__global__ void final_out(const float* __restrict__ f, const float* __restrict__ outW,
                          const float* __restrict__ outb, float* __restrict__ y, int n) {
  int gw = (blockIdx.x * 256 + threadIdx.x) >> 6;
  int lane = threadIdx.x & 63;
  if (gw >= n) return;
  const float2* fr = (const float2*)(f + (size_t)gw * 128);
  const float2* w2 = (const float2*)outW;
  float2 a = fr[lane], b = w2[lane];
  float p = a.x * b.x + a.y * b.y;
#pragma unroll
  for (int off = 32; off > 0; off >>= 1) p += __shfl_down(p, off, 64);
  if (lane == 0) y[gw] = 1.f / (1.f + expf(-(p + outb[0])));
}

extern "C" void kernel_launch(void* const* d_in, const int* in_sizes, int n_in,
                              void* d_out, int out_size, void* d_ws, size_t ws_size,
                              hipStream_t stream) {
  const float* meta_a = (const float*)d_in[0];
  const float* meta_b = (const float*)d_in[1];
  const float* x_a    = (const float*)d_in[2];
  const float* x_b    = (const float*)d_in[3];
  const int*   ei_a   = (const int*)d_in[4];
  const int*   ei_b   = (const int*)d_in[5];
  const float* fc1_W = (const float*)d_in[6];
  const float* fc1_b = (const float*)d_in[7];
  const float* fc2_W = (const float*)d_in[8];
  const float* fc2_b = (const float*)d_in[9];
  const float* gcn1_W = (const float*)d_in[10];
  const float* gcn1_b = (const float*)d_in[11];
  const float* gcn2_W = (const float*)d_in[12];
  const float* gcn2_b = (const float*)d_in[13];
  const float* fcc_W = (const float*)d_in[14];
  const float* fcc_b = (const float*)d_in[15];
  const float* out_W = (const float*)d_in[16];
  const float* out_b = (const float*)d_in[17];
  float* y = (float*)d_out;

  const int N = in_sizes[0] / 512;
  const int E = in_sizes[4] / 2;

  // ---- workspace layout (bytes via element offsets) ----
  char* ws = (char*)d_ws;
  unsigned short* combined = (unsigned short*)ws;              // N*512 bf16
  unsigned short* t0 = combined + (size_t)N * 512;             // N*128 bf16
  unsigned short* t1 = t0 + (size_t)N * 128;
  unsigned short* t2 = t1 + (size_t)N * 128;
  unsigned short* t3 = t2 + (size_t)N * 128;
  float* fccout = (float*)(t3 + (size_t)N * 128);              // N*128 fp32
  unsigned short* wt = (unsigned short*)(fccout + (size_t)N * 128);  // 196608 bf16
  float* dinv = (float*)(wt + 196608);                         // 2N fp32
  int* deg = (int*)(dinv + 2 * (size_t)N);                     // 2N
  int* cursor = deg + 2 * (size_t)N;                           // 2N
  int* rp = cursor + 2 * (size_t)N;                            // 2*(N+1)
  int* csrA = rp + 2 * (size_t)(N + 1) + 2;                    // E (pad to 16B)
  int* csrB = csrA + (size_t)E;                                // E

  // Wt element offsets: fc1=0, fc2=65536, g1=81920, g2=114688, fcc=131072
  unsigned short* wt_fc1 = wt;
  unsigned short* wt_fc2 = wt + 65536;
  unsigned short* wt_g1  = wt + 81920;
  unsigned short* wt_g2  = wt + 114688;
  unsigned short* wt_fcc = wt + 131072;

  const int gemm_grid = (N + GM - 1) / GM;
  const int eg2 = (2 * E + 255) / 256;
  const int ng2 = (2 * N + 255) / 256;

  // weight prep + CSR build (both graphs merged)
  prep_w<<<256, 256, 0, stream>>>(fc1_W, fc2_W, gcn1_W, gcn2_W, fcc_W, wt);
  hipMemsetAsync(deg, 0, (size_t)4 * N * sizeof(int), stream);  // deg + cursor
  deg_count2<<<eg2, 256, 0, stream>>>(ei_a, ei_b, E, N, deg);
  dinv2<<<ng2, 256, 0, stream>>>(deg, dinv, 2 * N);
  scan_deg2<<<2, 256, 0, stream>>>(deg, rp, N);
  fill_csr2<<<eg2, 256, 0, stream>>>(ei_a, ei_b, E, N, rp, cursor, csrA, csrB);

  // MLP branches -> combined cols [0,128) and [128,256)
  gemm_mfma<<<gemm_grid, 256, 0, stream>>>(meta_a, 512, 1, wt_fc1, fc1_b, nullptr, t0, nullptr, 128, 0, N, 512, 1);
  gemm_mfma<<<gemm_grid, 256, 0, stream>>>(t0, 128, 0, wt_fc2, fc2_b, nullptr, combined, nullptr, 512, 0, N, 128, 1);
  gemm_mfma<<<gemm_grid, 256, 0, stream>>>(meta_b, 512, 1, wt_fc1, fc1_b, nullptr, t0, nullptr, 128, 0, N, 512, 1);
  gemm_mfma<<<gemm_grid, 256, 0, stream>>>(t0, 128, 0, wt_fc2, fc2_b, nullptr, combined, nullptr, 512, 128, N, 128, 1);

  // GCN layer 1 (both graphs): hs = (X@W)*dinv[row] -> gather
  gemm_mfma<<<gemm_grid, 256, 0, stream>>>(x_a, 256, 1, wt_g1, nullptr, dinv,     t0, nullptr, 128, 0, N, 256, 0);
  gemm_mfma<<<gemm_grid, 256, 0, stream>>>(x_b, 256, 1, wt_g1, nullptr, dinv + N, t1, nullptr, 128, 0, N, 256, 0);
  gather2<<<(2 * N + 3) / 4, 256, 0, stream>>>(t0, t1, csrA, csrB, rp, dinv, gcn1_b,
                                               t2, t3, 128, 0, 128, 0, N);
  // GCN layer 2 -> combined cols [256,384) and [384,512)
  gemm_mfma<<<gemm_grid, 256, 0, stream>>>(t2, 128, 0, wt_g2, nullptr, dinv,     t0, nullptr, 128, 0, N, 128, 0);
  gemm_mfma<<<gemm_grid, 256, 0, stream>>>(t3, 128, 0, wt_g2, nullptr, dinv + N, t1, nullptr, 128, 0, N, 128, 0);
  gather2<<<(2 * N + 3) / 4, 256, 0, stream>>>(t0, t1, csrA, csrB, rp, dinv, gcn2_b,
                                               combined, combined, 512, 256, 512, 384, N);

  // head
  gemm_mfma<<<gemm_grid, 256, 0, stream>>>(combined, 512, 0, wt_fcc, fcc_b, nullptr, nullptr, fccout, 128, 0, N, 512, 1);
  final_out<<<(N + 3) / 4, 256, 0, stream>>>(fccout, out_W, out_b, y, N);
}

// Round 3
// 924.687 us; speedup vs baseline: 1.7760x; 1.2772x over previous
//
#include <hip/hip_runtime.h>
#include <math.h>

// ---------------------------------------------------------------------------
// bf16-MFMA GEMMs + locality-preserving CSR build.
// CSR build: bucket (512-node dst ranges) counting-sort with LDS staging ->
// coalesced record writes; per-bucket workgroup builds csr (ushort), rp, dinv.
// GCN: hs = (X@W)*dinv[row]; out[v] = relu(dinv[v]*(hs[v]+sum_in hs[s]) + b)
// ---------------------------------------------------------------------------

typedef __attribute__((ext_vector_type(8))) short bf16x8;
typedef __attribute__((ext_vector_type(4))) float f32x4;

static __device__ __forceinline__ unsigned short f2bf(float f) {
  unsigned u = __float_as_uint(f);
  unsigned r = u + 0x7fffu + ((u >> 16) & 1u);   // RNE
  return (unsigned short)(r >> 16);
}
static __device__ __forceinline__ float bf2f(unsigned short h) {
  return __uint_as_float(((unsigned)h) << 16);
}

#define GM 128  // rows per block (4 waves x 32 rows)

__launch_bounds__(256)
__global__ void gemm_mfma(const void* __restrict__ Av, int lda, int a_fp32,
                          const unsigned short* __restrict__ Wt,  // [128,K] bf16
                          const float* __restrict__ bias,         // [128] or null
                          const float* __restrict__ rowscale,     // [M] or null
                          unsigned short* __restrict__ Cb,        // bf16 out or null
                          float* __restrict__ Cf,                 // fp32 out or null
                          int ldc, int col_off,
                          int M, int K, int do_relu) {
  const int tid = threadIdx.x;
  const int wave = tid >> 6;
  const int lane = tid & 63;
  const int quad = lane >> 4;
  const int lr = lane & 15;
  const int m0 = blockIdx.x * GM + wave * 32;  // this wave's 32 rows

  f32x4 acc[2][8];
#pragma unroll
  for (int r = 0; r < 2; r++)
#pragma unroll
    for (int c = 0; c < 8; c++) acc[r][c] = (f32x4){0.f, 0.f, 0.f, 0.f};

  int arow0 = m0 + lr;        if (arow0 > M - 1) arow0 = M - 1;
  int arow1 = m0 + 16 + lr;   if (arow1 > M - 1) arow1 = M - 1;

  for (int k0 = 0; k0 < K; k0 += 32) {
    const int kq = k0 + quad * 8;
    bf16x8 a[2];
    if (a_fp32) {
      const float* a0 = (const float*)Av + (size_t)arow0 * lda + kq;
      const float* a1 = (const float*)Av + (size_t)arow1 * lda + kq;
      float4 l0 = *(const float4*)a0, h0 = *(const float4*)(a0 + 4);
      float4 l1 = *(const float4*)a1, h1 = *(const float4*)(a1 + 4);
      a[0][0] = (short)f2bf(l0.x); a[0][1] = (short)f2bf(l0.y);
      a[0][2] = (short)f2bf(l0.z); a[0][3] = (short)f2bf(l0.w);
      a[0][4] = (short)f2bf(h0.x); a[0][5] = (short)f2bf(h0.y);
      a[0][6] = (short)f2bf(h0.z); a[0][7] = (short)f2bf(h0.w);
      a[1][0] = (short)f2bf(l1.x); a[1][1] = (short)f2bf(l1.y);
      a[1][2] = (short)f2bf(l1.z); a[1][3] = (short)f2bf(l1.w);
      a[1][4] = (short)f2bf(h1.x); a[1][5] = (short)f2bf(h1.y);
      a[1][6] = (short)f2bf(h1.z); a[1][7] = (short)f2bf(h1.w);
    } else {
      a[0] = *(const bf16x8*)((const unsigned short*)Av + (size_t)arow0 * lda + kq);
      a[1] = *(const bf16x8*)((const unsigned short*)Av + (size_t)arow1 * lda + kq);
    }
#pragma unroll
    for (int c = 0; c < 8; c++) {
      bf16x8 b = *(const bf16x8*)(Wt + (size_t)(c * 16 + lr) * K + kq);
      acc[0][c] = __builtin_amdgcn_mfma_f32_16x16x32_bf16(a[0], b, acc[0][c], 0, 0, 0);
      acc[1][c] = __builtin_amdgcn_mfma_f32_16x16x32_bf16(a[1], b, acc[1][c], 0, 0, 0);
    }
  }

#pragma unroll
  for (int r = 0; r < 2; r++) {
    const int rbase = m0 + r * 16 + quad * 4;
    float rs[4];
#pragma unroll
    for (int i = 0; i < 4; i++) {
      int row = rbase + i;
      rs[i] = (rowscale && row < M) ? rowscale[row] : 1.0f;
    }
#pragma unroll
    for (int c = 0; c < 8; c++) {
      const int col = col_off + c * 16 + lr;
      const float bi = bias ? bias[c * 16 + lr] : 0.f;
#pragma unroll
      for (int i = 0; i < 4; i++) {
        int row = rbase + i;
        if (row < M) {
          float v = acc[r][c][i] * rs[i] + bi;
          if (do_relu) v = fmaxf(v, 0.f);
          if (Cb) Cb[(size_t)row * ldc + col] = f2bf(v);
          else    Cf[(size_t)row * ldc + col] = v;
        }
      }
    }
  }
}

// transpose+convert the 5 weight matrices [K,128] fp32 -> [128,K] bf16
__global__ void prep_w(const float* __restrict__ fc1, const float* __restrict__ fc2,
                       const float* __restrict__ g1, const float* __restrict__ g2,
                       const float* __restrict__ fcc, unsigned short* __restrict__ wt) {
  int i = blockIdx.x * 256 + threadIdx.x;
  const float* src[5] = {fc1, fc2, g1, g2, fcc};
  const int Ks[5] = {512, 128, 256, 128, 512};
  int off = 0;
#pragma unroll
  for (int w = 0; w < 5; w++) {
    int K = Ks[w];
    if (i < K * 128) {
      int k = i >> 7, c = i & 127;
      wt[off + c * K + k] = f2bf(src[w][i]);
    }
    off += K * 128;
  }
}

// ---------------- CSR build (bucketed, write-coalesced) ----------------
// bucket b covers dst nodes [b*512, b*512+512); NB = ceil(N/512) <= 128.

// Phase A0: global per-bucket edge counts (LDS pre-aggregated)
__launch_bounds__(256)
__global__ void bucket_hist(const int* __restrict__ eiA, const int* __restrict__ eiB,
                            int E, int T, int NB, int* __restrict__ bucket_cnt) {
  __shared__ int hist[128];
  const int g = blockIdx.x >= T;
  const int tile = blockIdx.x - g * T;
  const int* ei = g ? eiB : eiA;
  const int tid = threadIdx.x;
  for (int i = tid; i < NB; i += 256) hist[i] = 0;
  __syncthreads();
  const int base = tile * 4096;
#pragma unroll
  for (int j = 0; j < 16; j++) {
    int li = base + j * 256 + tid;
    if (li < E) atomicAdd(&hist[ei[E + li] >> 9], 1);
  }
  __syncthreads();
  for (int i = tid; i < NB; i += 256)
    if (hist[i]) atomicAdd(&bucket_cnt[g * NB + i], hist[i]);
}

// scan bucket counts -> bucket bases (per graph), init global cursors, rp[N]=E
__launch_bounds__(256)
__global__ void scan_buckets(const int* __restrict__ bucket_cnt, int E, int N, int NB,
                             int* __restrict__ bbase, int* __restrict__ gcur,
                             int* __restrict__ rpA, int* __restrict__ rpB) {
  __shared__ int sc[256];
  const int tid = threadIdx.x;
  if (tid < 2 * NB) sc[tid] = bucket_cnt[tid];
  __syncthreads();
  if (tid == 0) {
    for (int g = 0; g < 2; g++) {
      int acc = 0;
      for (int b = 0; b < NB; b++) {
        bbase[g * (NB + 1) + b] = acc;
        gcur[g * NB + b] = g * E + acc;
        acc += sc[g * NB + b];
      }
      bbase[g * (NB + 1) + NB] = acc;  // == E
    }
    rpA[N] = E;
    rpB[N] = E;
  }
}

// Phase A: tile counting-sort in LDS, coalesced flush to bucket regions
__launch_bounds__(256)
__global__ void bucket_scatter(const int* __restrict__ eiA, const int* __restrict__ eiB,
                               int E, int T, int NB, int* __restrict__ gcur,
                               unsigned* __restrict__ records) {
  __shared__ unsigned staging[4096];
  __shared__ int hist[129];
  __shared__ int offs[129];
  __shared__ int gbase[128];
  __shared__ int sm[128];
  const int g = blockIdx.x >= T;
  const int tile = blockIdx.x - g * T;
  const int* ei = g ? eiB : eiA;
  const int tid = threadIdx.x;
  for (int i = tid; i <= NB; i += 256) hist[i] = 0;
  __syncthreads();
  const int base = tile * 4096;
  int myb[16], myp[16];
  unsigned myrec[16];
#pragma unroll
  for (int j = 0; j < 16; j++) {
    int li = base + j * 256 + tid;
    int b = NB;
    unsigned rec = 0;
    if (li < E) {
      int s = ei[li], d = ei[E + li];
      b = d >> 9;
      rec = (unsigned)s | ((unsigned)d << 16);
    }
    myb[j] = b; myrec[j] = rec;
    myp[j] = atomicAdd(&hist[b], 1);
  }
  __syncthreads();
  // inclusive scan hist[0..127] -> exclusive offs
  if (tid < 128) sm[tid] = (tid <= NB) ? hist[tid] : 0;
  __syncthreads();
  for (int d = 1; d < 128; d <<= 1) {
    int v = 0;
    if (tid < 128) { v = sm[tid]; if (tid >= d) v += sm[tid - d]; }
    __syncthreads();
    if (tid < 128) sm[tid] = v;
    __syncthreads();
  }
  if (tid < 128) offs[tid] = sm[tid] - ((tid <= NB) ? hist[tid] : 0);
  __syncthreads();
  // stage records sorted by bucket
#pragma unroll
  for (int j = 0; j < 16; j++)
    if (myb[j] < NB) staging[offs[myb[j]] + myp[j]] = myrec[j];
  // grab global slots per bucket
  if (tid < NB && hist[tid] > 0) gbase[tid] = atomicAdd(&gcur[g * NB + tid], hist[tid]);
  __syncthreads();
  const int total = offs[NB];  // valid records only
  for (int i = tid; i < total; i += 256) {
    unsigned rec = staging[i];
    int b = (int)(rec >> 16) >> 9;
    records[gbase[b] + (i - offs[b])] = rec;
  }
}

// Phase B: per-bucket CSR fill (ushort src), rp, dinv — all LDS-local
__launch_bounds__(256)
__global__ void csr_build(const unsigned* __restrict__ records, const int* __restrict__ bbase,
                          int E, int N, int NB,
                          int* __restrict__ rpA, int* __restrict__ rpB,
                          float* __restrict__ dinv,
                          unsigned short* __restrict__ csrA, unsigned short* __restrict__ csrB) {
  __shared__ int ncnt[512];
  __shared__ int excl[512];
  __shared__ int sm[256];
  const int g = blockIdx.x >= NB;
  const int b = blockIdx.x - g * NB;
  const int tid = threadIdx.x;
  const int base = bbase[g * (NB + 1) + b];
  const int cnt  = bbase[g * (NB + 1) + b + 1] - base;
  const int node0 = b << 9;
  const int nb = min(512, N - node0);
  const unsigned* rec = records + (size_t)g * E + base;
  int* rp = g ? rpB : rpA;
  unsigned short* csr = g ? csrB : csrA;

  for (int i = tid; i < 512; i += 256) ncnt[i] = 0;
  __syncthreads();
  for (int i = tid; i < cnt; i += 256)
    atomicAdd(&ncnt[(rec[i] >> 16) & 511], 1);
  __syncthreads();
  // exclusive scan of ncnt[512], 2 elems/thread
  int a0 = ncnt[2 * tid], a1 = ncnt[2 * tid + 1];
  int ps = a0 + a1;
  sm[tid] = ps;
  __syncthreads();
  for (int d = 1; d < 256; d <<= 1) {
    int v = sm[tid];
    if (tid >= d) v += sm[tid - d];
    __syncthreads();
    sm[tid] = v;
    __syncthreads();
  }
  int e0 = sm[tid] - ps;
  excl[2 * tid] = e0;
  excl[2 * tid + 1] = e0 + a0;
  __syncthreads();
  // rp + dinv (counts still intact in ncnt)
  for (int i = tid; i < nb; i += 256) {
    rp[node0 + i] = base + excl[i];
    dinv[g * N + node0 + i] = rsqrtf((float)(ncnt[i] + 1));  // +1 self-loop
  }
  __syncthreads();
  for (int i = tid; i < 512; i += 256) ncnt[i] = excl[i];  // reuse as cursor
  __syncthreads();
  for (int i = tid; i < cnt; i += 256) {
    unsigned r = rec[i];
    int p = atomicAdd(&ncnt[(r >> 16) & 511], 1);
    csr[base + p] = (unsigned short)(r & 0xffffu);
  }
}

// gather for both graphs: one wave per node, lane t owns cols {2t,2t+1}
__launch_bounds__(256)
__global__ void gather2(const unsigned short* __restrict__ hsA,
                        const unsigned short* __restrict__ hsB,
                        const unsigned short* __restrict__ csrA,
                        const unsigned short* __restrict__ csrB,
                        const int* __restrict__ rpA, const int* __restrict__ rpB,
                        const float* __restrict__ dinv,
                        const float* __restrict__ bias,
                        unsigned short* __restrict__ outA, unsigned short* __restrict__ outB,
                        int ldA, int coA, int ldB, int coB, int N) {
  int widx = (blockIdx.x * 256 + threadIdx.x) >> 6;
  if (widx >= 2 * N) return;
  int g = widx >= N;
  int v = g ? widx - N : widx;
  const unsigned short* hs = g ? hsB : hsA;
  const unsigned short* csr = g ? csrB : csrA;
  const int* rp = g ? rpB : rpA;
  unsigned short* out = g ? outB : outA;
  const int ldc = g ? ldB : ldA;
  const int co = g ? coB : coA;
  const int t = threadIdx.x & 63;

  unsigned self = *(const unsigned*)(hs + (size_t)v * 128 + 2 * t);
  float ax = bf2f((unsigned short)(self & 0xffff));
  float ay = bf2f((unsigned short)(self >> 16));

  int e = rp[v], end = rp[v + 1];
  for (; e + 4 <= end; e += 4) {
    int s0 = csr[e], s1 = csr[e + 1], s2 = csr[e + 2], s3 = csr[e + 3];
    unsigned m0 = *(const unsigned*)(hs + (size_t)s0 * 128 + 2 * t);
    unsigned m1 = *(const unsigned*)(hs + (size_t)s1 * 128 + 2 * t);
    unsigned m2 = *(const unsigned*)(hs + (size_t)s2 * 128 + 2 * t);
    unsigned m3 = *(const unsigned*)(hs + (size_t)s3 * 128 + 2 * t);
    ax += bf2f((unsigned short)(m0 & 0xffff)) + bf2f((unsigned short)(m1 & 0xffff)) +
          bf2f((unsigned short)(m2 & 0xffff)) + bf2f((unsigned short)(m3 & 0xffff));
    ay += bf2f((unsigned short)(m0 >> 16)) + bf2f((unsigned short)(m1 >> 16)) +
          bf2f((unsigned short)(m2 >> 16)) + bf2f((unsigned short)(m3 >> 16));
  }
  for (; e < end; e++) {
    int s = csr[e];
    unsigned m = *(const unsigned*)(hs + (size_t)s * 128 + 2 * t);
    ax += bf2f((unsigned short)(m & 0xffff));
    ay += bf2f((unsigned short)(m >> 16));
  }

  float dv = dinv[g * N + v];
  float2 bi = ((const float2*)bias)[t];
  float ox = fmaxf(ax * dv + bi.x, 0.f);
  float oy = fmaxf(ay * dv + bi.y, 0.f);
  unsigned packed = (unsigned)f2bf(ox) | ((unsigned)f2bf(oy) << 16);
  *(unsigned*)(out + (size_t)v * ldc + co + 2 * t) = packed;
}

__launch_bounds__(256)
__global__ void final_out(const float* __restrict__ f, const float* __restrict__ outW,
                          const float* __restrict__ outb, float* __restrict__ y, int n) {
  int gw = (blockIdx.x * 256 + threadIdx.x) >> 6;
  int lane = threadIdx.x & 63;
  if (gw >= n) return;
  const float2* fr = (const float2*)(f + (size_t)gw * 128);
  const float2* w2 = (const float2*)outW;
  float2 a = fr[lane], b = w2[lane];
  float p = a.x * b.x + a.y * b.y;
#pragma unroll
  for (int off = 32; off > 0; off >>= 1) p += __shfl_down(p, off, 64);
  if (lane == 0) y[gw] = 1.f / (1.f + expf(-(p + outb[0])));
}

extern "C" void kernel_launch(void* const* d_in, const int* in_sizes, int n_in,
                              void* d_out, int out_size, void* d_ws, size_t ws_size,
                              hipStream_t stream) {
  const float* meta_a = (const float*)d_in[0];
  const float* meta_b = (const float*)d_in[1];
  const float* x_a    = (const float*)d_in[2];
  const float* x_b    = (const float*)d_in[3];
  const int*   ei_a   = (const int*)d_in[4];
  const int*   ei_b   = (const int*)d_in[5];
  const float* fc1_W = (const float*)d_in[6];
  const float* fc1_b = (const float*)d_in[7];
  const float* fc2_W = (const float*)d_in[8];
  const float* fc2_b = (const float*)d_in[9];
  const float* gcn1_W = (const float*)d_in[10];
  const float* gcn1_b = (const float*)d_in[11];
  const float* gcn2_W = (const float*)d_in[12];
  const float* gcn2_b = (const float*)d_in[13];
  const float* fcc_W = (const float*)d_in[14];
  const float* fcc_b = (const float*)d_in[15];
  const float* out_W = (const float*)d_in[16];
  const float* out_b = (const float*)d_in[17];
  float* y = (float*)d_out;

  const int N = in_sizes[0] / 512;
  const int E = in_sizes[4] / 2;
  const int NB = (N + 511) >> 9;           // <=128 required (N=50000 -> 98)
  const int T = (E + 4095) / 4096;         // tiles per graph

  // ---- workspace layout ----
  char* p = (char*)d_ws;
  auto alloc = [&](size_t bytes) { char* r = p; p += (bytes + 255) & ~255ull; return r; };
  unsigned short* combined = (unsigned short*)alloc((size_t)N * 512 * 2);
  unsigned short* t0 = (unsigned short*)alloc((size_t)N * 128 * 2);
  unsigned short* t1 = (unsigned short*)alloc((size_t)N * 128 * 2);
  unsigned short* t2 = (unsigned short*)alloc((size_t)N * 128 * 2);
  unsigned short* t3 = (unsigned short*)alloc((size_t)N * 128 * 2);
  unsigned short* wt = (unsigned short*)alloc(196608 * 2);
  float* dinv = (float*)alloc((size_t)2 * N * 4);
  int* rpA = (int*)alloc((size_t)(N + 1) * 4);
  int* rpB = (int*)alloc((size_t)(N + 1) * 4);
  int* bucket_cnt = (int*)alloc((size_t)2 * NB * 4);
  int* bbase = (int*)alloc((size_t)2 * (NB + 1) * 4);
  int* gcur = (int*)alloc((size_t)2 * NB * 4);
  // big region: records + csrA + csrB, aliased later by fccout (fp32 [N,128])
  size_t rec_bytes = ((size_t)2 * E * 4 + 255) & ~255ull;
  size_t csr_bytes = ((size_t)E * 2 + 255) & ~255ull;
  size_t big_bytes = rec_bytes + 2 * csr_bytes;
  size_t fcc_bytes = (size_t)N * 128 * 4;
  char* big = alloc(big_bytes > fcc_bytes ? big_bytes : fcc_bytes);
  unsigned* records = (unsigned*)big;
  unsigned short* csrA = (unsigned short*)(big + rec_bytes);
  unsigned short* csrB = (unsigned short*)(big + rec_bytes + csr_bytes);
  float* fccout = (float*)big;  // aliases records/csr (dead by head stage)

  unsigned short* wt_fc1 = wt;
  unsigned short* wt_fc2 = wt + 65536;
  unsigned short* wt_g1  = wt + 81920;
  unsigned short* wt_g2  = wt + 114688;
  unsigned short* wt_fcc = wt + 131072;

  const int gemm_grid = (N + GM - 1) / GM;

  // weight prep + CSR build
  prep_w<<<256, 256, 0, stream>>>(fc1_W, fc2_W, gcn1_W, gcn2_W, fcc_W, wt);
  hipMemsetAsync(bucket_cnt, 0, (size_t)2 * NB * 4, stream);
  bucket_hist<<<2 * T, 256, 0, stream>>>(ei_a, ei_b, E, T, NB, bucket_cnt);
  scan_buckets<<<1, 256, 0, stream>>>(bucket_cnt, E, N, NB, bbase, gcur, rpA, rpB);
  bucket_scatter<<<2 * T, 256, 0, stream>>>(ei_a, ei_b, E, T, NB, gcur, records);
  csr_build<<<2 * NB, 256, 0, stream>>>(records, bbase, E, N, NB, rpA, rpB, dinv, csrA, csrB);

  // MLP branches -> combined cols [0,128) and [128,256)
  gemm_mfma<<<gemm_grid, 256, 0, stream>>>(meta_a, 512, 1, wt_fc1, fc1_b, nullptr, t0, nullptr, 128, 0, N, 512, 1);
  gemm_mfma<<<gemm_grid, 256, 0, stream>>>(t0, 128, 0, wt_fc2, fc2_b, nullptr, combined, nullptr, 512, 0, N, 128, 1);
  gemm_mfma<<<gemm_grid, 256, 0, stream>>>(meta_b, 512, 1, wt_fc1, fc1_b, nullptr, t0, nullptr, 128, 0, N, 512, 1);
  gemm_mfma<<<gemm_grid, 256, 0, stream>>>(t0, 128, 0, wt_fc2, fc2_b, nullptr, combined, nullptr, 512, 128, N, 128, 1);

  // GCN layer 1 (both graphs)
  gemm_mfma<<<gemm_grid, 256, 0, stream>>>(x_a, 256, 1, wt_g1, nullptr, dinv,     t0, nullptr, 128, 0, N, 256, 0);
  gemm_mfma<<<gemm_grid, 256, 0, stream>>>(x_b, 256, 1, wt_g1, nullptr, dinv + N, t1, nullptr, 128, 0, N, 256, 0);
  gather2<<<(2 * N + 3) / 4, 256, 0, stream>>>(t0, t1, csrA, csrB, rpA, rpB, dinv, gcn1_b,
                                               t2, t3, 128, 0, 128, 0, N);
  // GCN layer 2 -> combined cols [256,384) and [384,512)
  gemm_mfma<<<gemm_grid, 256, 0, stream>>>(t2, 128, 0, wt_g2, nullptr, dinv,     t0, nullptr, 128, 0, N, 128, 0);
  gemm_mfma<<<gemm_grid, 256, 0, stream>>>(t3, 128, 0, wt_g2, nullptr, dinv + N, t1, nullptr, 128, 0, N, 128, 0);
  gather2<<<(2 * N + 3) / 4, 256, 0, stream>>>(t0, t1, csrA, csrB, rpA, rpB, dinv, gcn2_b,
                                               combined, combined, 512, 256, 512, 384, N);

  // head
  gemm_mfma<<<gemm_grid, 256, 0, stream>>>(combined, 512, 0, wt_fcc, fcc_b, nullptr, nullptr, fccout, 128, 0, N, 512, 1);
  final_out<<<(N + 3) / 4, 256, 0, stream>>>(fccout, out_W, out_b, y, N);
}

// Round 4
// 843.652 us; speedup vs baseline: 1.9466x; 1.0961x over previous
//
#include <hip/hip_runtime.h>
#include <math.h>

// ---------------------------------------------------------------------------
// bf16-MFMA GEMMs (fragment-major weight layout -> fully coalesced B loads)
// + locality-preserving CSR build + 4-rows-per-wave gather.
// GCN: hs = (X@W)*dinv[row]; out[v] = relu(dinv[v]*(hs[v]+sum_in hs[s]) + b)
// ---------------------------------------------------------------------------

typedef __attribute__((ext_vector_type(8))) short bf16x8;
typedef __attribute__((ext_vector_type(4))) float f32x4;

static __device__ __forceinline__ unsigned short f2bf(float f) {
  unsigned u = __float_as_uint(f);
  unsigned r = u + 0x7fffu + ((u >> 16) & 1u);   // RNE
  return (unsigned short)(r >> 16);
}
static __device__ __forceinline__ float bf2f(unsigned short h) {
  return __uint_as_float(((unsigned)h) << 16);
}
static __device__ __forceinline__ float bflo(unsigned m) { return __uint_as_float(m << 16); }
static __device__ __forceinline__ float bfhi(unsigned m) { return __uint_as_float(m & 0xffff0000u); }

#define GM 128  // rows per block (4 waves x 32 rows)

// Wt layout (fragment-major): entry index ((kt*8 + c)*64 + lane), 8 bf16 each:
//   holds W[k = kt*32 + (lane>>4)*8 + j][n = c*16 + (lane&15)], j=0..7
__launch_bounds__(256)
__global__ void gemm_mfma(const void* __restrict__ Av, int lda, int a_fp32,
                          const unsigned short* __restrict__ Wt,
                          const float* __restrict__ bias,         // [128] or null
                          const float* __restrict__ rowscale,     // [M] or null
                          unsigned short* __restrict__ Cb,        // bf16 out or null
                          float* __restrict__ Cf,                 // fp32 out or null
                          int ldc, int col_off,
                          int M, int K, int do_relu) {
  const int tid = threadIdx.x;
  const int wave = tid >> 6;
  const int lane = tid & 63;
  const int quad = lane >> 4;
  const int lr = lane & 15;
  const int m0 = blockIdx.x * GM + wave * 32;  // this wave's 32 rows

  f32x4 acc[2][8];
#pragma unroll
  for (int r = 0; r < 2; r++)
#pragma unroll
    for (int c = 0; c < 8; c++) acc[r][c] = (f32x4){0.f, 0.f, 0.f, 0.f};

  int arow0 = m0 + lr;        if (arow0 > M - 1) arow0 = M - 1;
  int arow1 = m0 + 16 + lr;   if (arow1 > M - 1) arow1 = M - 1;

  const int KT = K >> 5;
  const bf16x8* Bf = (const bf16x8*)Wt;
  for (int kt = 0; kt < KT; kt++) {
    const int kq = kt * 32 + quad * 8;
    bf16x8 a[2];
    if (a_fp32) {
      const float* a0 = (const float*)Av + (size_t)arow0 * lda + kq;
      const float* a1 = (const float*)Av + (size_t)arow1 * lda + kq;
      float4 l0 = *(const float4*)a0, h0 = *(const float4*)(a0 + 4);
      float4 l1 = *(const float4*)a1, h1 = *(const float4*)(a1 + 4);
      a[0][0] = (short)f2bf(l0.x); a[0][1] = (short)f2bf(l0.y);
      a[0][2] = (short)f2bf(l0.z); a[0][3] = (short)f2bf(l0.w);
      a[0][4] = (short)f2bf(h0.x); a[0][5] = (short)f2bf(h0.y);
      a[0][6] = (short)f2bf(h0.z); a[0][7] = (short)f2bf(h0.w);
      a[1][0] = (short)f2bf(l1.x); a[1][1] = (short)f2bf(l1.y);
      a[1][2] = (short)f2bf(l1.z); a[1][3] = (short)f2bf(l1.w);
      a[1][4] = (short)f2bf(h1.x); a[1][5] = (short)f2bf(h1.y);
      a[1][6] = (short)f2bf(h1.z); a[1][7] = (short)f2bf(h1.w);
    } else {
      a[0] = *(const bf16x8*)((const unsigned short*)Av + (size_t)arow0 * lda + kq);
      a[1] = *(const bf16x8*)((const unsigned short*)Av + (size_t)arow1 * lda + kq);
    }
    const bf16x8* Bk = Bf + (size_t)kt * 512 + lane;
#pragma unroll
    for (int c = 0; c < 8; c++) {
      bf16x8 b = Bk[c * 64];
      acc[0][c] = __builtin_amdgcn_mfma_f32_16x16x32_bf16(a[0], b, acc[0][c], 0, 0, 0);
      acc[1][c] = __builtin_amdgcn_mfma_f32_16x16x32_bf16(a[1], b, acc[1][c], 0, 0, 0);
    }
  }

#pragma unroll
  for (int r = 0; r < 2; r++) {
    const int rbase = m0 + r * 16 + quad * 4;
    float rs[4];
#pragma unroll
    for (int i = 0; i < 4; i++) {
      int row = rbase + i;
      rs[i] = (rowscale && row < M) ? rowscale[row] : 1.0f;
    }
#pragma unroll
    for (int c = 0; c < 8; c++) {
      const int col = col_off + c * 16 + lr;
      const float bi = bias ? bias[c * 16 + lr] : 0.f;
#pragma unroll
      for (int i = 0; i < 4; i++) {
        int row = rbase + i;
        if (row < M) {
          float v = acc[r][c][i] * rs[i] + bi;
          if (do_relu) v = fmaxf(v, 0.f);
          if (Cb) Cb[(size_t)row * ldc + col] = f2bf(v);
          else    Cf[(size_t)row * ldc + col] = v;
        }
      }
    }
  }
}

// weights [K,128] fp32 -> fragment-major bf16 (see gemm_mfma header comment)
__global__ void prep_w(const float* __restrict__ fc1, const float* __restrict__ fc2,
                       const float* __restrict__ g1, const float* __restrict__ g2,
                       const float* __restrict__ fcc, unsigned short* __restrict__ wt) {
  int t = blockIdx.x * 256 + threadIdx.x;   // one thread per 16-B fragment group
  const float* src[5] = {fc1, fc2, g1, g2, fcc};
  const int Ks[5] = {512, 128, 256, 128, 512};
  int off = 0;
#pragma unroll
  for (int w = 0; w < 5; w++) {
    int K = Ks[w];
    int ngroups = K * 16;  // K*128/8
    if (t < ngroups) {
      int lane = t & 63;
      int c = (t >> 6) & 7;
      int kt = t >> 9;
      int quad = lane >> 4, lr = lane & 15;
      int n = c * 16 + lr;
      unsigned short* dst = wt + off + (size_t)t * 8;
      const float* s = src[w];
#pragma unroll
      for (int j = 0; j < 8; j++) {
        int k = kt * 32 + quad * 8 + j;
        dst[j] = f2bf(s[k * 128 + n]);
      }
    }
    off += K * 128;
  }
}

// ---------------- CSR build (bucketed, write-coalesced) ----------------
__launch_bounds__(256)
__global__ void bucket_hist(const int* __restrict__ eiA, const int* __restrict__ eiB,
                            int E, int T, int NB, int* __restrict__ bucket_cnt) {
  __shared__ int hist[128];
  const int g = blockIdx.x >= T;
  const int tile = blockIdx.x - g * T;
  const int* ei = g ? eiB : eiA;
  const int tid = threadIdx.x;
  for (int i = tid; i < NB; i += 256) hist[i] = 0;
  __syncthreads();
  const int base = tile * 4096;
#pragma unroll
  for (int j = 0; j < 16; j++) {
    int li = base + j * 256 + tid;
    if (li < E) atomicAdd(&hist[ei[E + li] >> 9], 1);
  }
  __syncthreads();
  for (int i = tid; i < NB; i += 256)
    if (hist[i]) atomicAdd(&bucket_cnt[g * NB + i], hist[i]);
}

__launch_bounds__(256)
__global__ void scan_buckets(const int* __restrict__ bucket_cnt, int E, int N, int NB,
                             int* __restrict__ bbase, int* __restrict__ gcur,
                             int* __restrict__ rpA, int* __restrict__ rpB) {
  __shared__ int sc[256];
  const int tid = threadIdx.x;
  if (tid < 2 * NB) sc[tid] = bucket_cnt[tid];
  __syncthreads();
  if (tid == 0) {
    for (int g = 0; g < 2; g++) {
      int acc = 0;
      for (int b = 0; b < NB; b++) {
        bbase[g * (NB + 1) + b] = acc;
        gcur[g * NB + b] = g * E + acc;
        acc += sc[g * NB + b];
      }
      bbase[g * (NB + 1) + NB] = acc;  // == E
    }
    rpA[N] = E;
    rpB[N] = E;
  }
}

__launch_bounds__(256)
__global__ void bucket_scatter(const int* __restrict__ eiA, const int* __restrict__ eiB,
                               int E, int T, int NB, int* __restrict__ gcur,
                               unsigned* __restrict__ records) {
  __shared__ unsigned staging[4096];
  __shared__ int hist[129];
  __shared__ int offs[129];
  __shared__ int gbase[128];
  __shared__ int sm[128];
  const int g = blockIdx.x >= T;
  const int tile = blockIdx.x - g * T;
  const int* ei = g ? eiB : eiA;
  const int tid = threadIdx.x;
  for (int i = tid; i <= NB; i += 256) hist[i] = 0;
  __syncthreads();
  const int base = tile * 4096;
  int myb[16], myp[16];
  unsigned myrec[16];
#pragma unroll
  for (int j = 0; j < 16; j++) {
    int li = base + j * 256 + tid;
    int b = NB;
    unsigned rec = 0;
    if (li < E) {
      int s = ei[li], d = ei[E + li];
      b = d >> 9;
      rec = (unsigned)s | ((unsigned)d << 16);
    }
    myb[j] = b; myrec[j] = rec;
    myp[j] = atomicAdd(&hist[b], 1);
  }
  __syncthreads();
  if (tid < 128) sm[tid] = (tid <= NB) ? hist[tid] : 0;
  __syncthreads();
  for (int d = 1; d < 128; d <<= 1) {
    int v = 0;
    if (tid < 128) { v = sm[tid]; if (tid >= d) v += sm[tid - d]; }
    __syncthreads();
    if (tid < 128) sm[tid] = v;
    __syncthreads();
  }
  if (tid < 128) offs[tid] = sm[tid] - ((tid <= NB) ? hist[tid] : 0);
  __syncthreads();
#pragma unroll
  for (int j = 0; j < 16; j++)
    if (myb[j] < NB) staging[offs[myb[j]] + myp[j]] = myrec[j];
  if (tid < NB && hist[tid] > 0) gbase[tid] = atomicAdd(&gcur[g * NB + tid], hist[tid]);
  __syncthreads();
  const int total = offs[NB];
  for (int i = tid; i < total; i += 256) {
    unsigned rec = staging[i];
    int b = (int)(rec >> 16) >> 9;
    records[gbase[b] + (i - offs[b])] = rec;
  }
}

__launch_bounds__(256)
__global__ void csr_build(const unsigned* __restrict__ records, const int* __restrict__ bbase,
                          int E, int N, int NB,
                          int* __restrict__ rpA, int* __restrict__ rpB,
                          float* __restrict__ dinv,
                          unsigned short* __restrict__ csrA, unsigned short* __restrict__ csrB) {
  __shared__ int ncnt[512];
  __shared__ int excl[512];
  __shared__ int sm[256];
  const int g = blockIdx.x >= NB;
  const int b = blockIdx.x - g * NB;
  const int tid = threadIdx.x;
  const int base = bbase[g * (NB + 1) + b];
  const int cnt  = bbase[g * (NB + 1) + b + 1] - base;
  const int node0 = b << 9;
  const int nb = min(512, N - node0);
  const unsigned* rec = records + (size_t)g * E + base;
  int* rp = g ? rpB : rpA;
  unsigned short* csr = g ? csrB : csrA;

  for (int i = tid; i < 512; i += 256) ncnt[i] = 0;
  __syncthreads();
  for (int i = tid; i < cnt; i += 256)
    atomicAdd(&ncnt[(rec[i] >> 16) & 511], 1);
  __syncthreads();
  int a0 = ncnt[2 * tid], a1 = ncnt[2 * tid + 1];
  int ps = a0 + a1;
  sm[tid] = ps;
  __syncthreads();
  for (int d = 1; d < 256; d <<= 1) {
    int v = sm[tid];
    if (tid >= d) v += sm[tid - d];
    __syncthreads();
    sm[tid] = v;
    __syncthreads();
  }
  int e0 = sm[tid] - ps;
  excl[2 * tid] = e0;
  excl[2 * tid + 1] = e0 + a0;
  __syncthreads();
  for (int i = tid; i < nb; i += 256) {
    rp[node0 + i] = base + excl[i];
    dinv[g * N + node0 + i] = rsqrtf((float)(ncnt[i] + 1));  // +1 self-loop
  }
  __syncthreads();
  for (int i = tid; i < 512; i += 256) ncnt[i] = excl[i];  // reuse as cursor
  __syncthreads();
  for (int i = tid; i < cnt; i += 256) {
    unsigned r = rec[i];
    int p = atomicAdd(&ncnt[(r >> 16) & 511], 1);
    csr[base + p] = (unsigned short)(r & 0xffffu);
  }
}

// ---------------- gather: one wave per node, 4 rows per VMEM instr ----------------
// lane = grp*16 + u; grp handles edge e+grp; u covers cols [u*8, u*8+8) (16 B).
#define ACC8(m)                                        \
  acc[0] += bflo((m).x); acc[1] += bfhi((m).x);        \
  acc[2] += bflo((m).y); acc[3] += bfhi((m).y);        \
  acc[4] += bflo((m).z); acc[5] += bfhi((m).z);        \
  acc[6] += bflo((m).w); acc[7] += bfhi((m).w);

__launch_bounds__(256)
__global__ void gather4(const unsigned short* __restrict__ hsA,
                        const unsigned short* __restrict__ hsB,
                        const unsigned short* __restrict__ csrA,
                        const unsigned short* __restrict__ csrB,
                        const int* __restrict__ rpA, const int* __restrict__ rpB,
                        const float* __restrict__ dinv,
                        const float* __restrict__ bias,
                        unsigned short* __restrict__ outA, unsigned short* __restrict__ outB,
                        int ldA, int coA, int ldB, int coB, int N) {
  int widx = (blockIdx.x * 256 + threadIdx.x) >> 6;
  if (widx >= 2 * N) return;
  int g = widx >= N;
  int v = g ? widx - N : widx;
  const unsigned short* hs = g ? hsB : hsA;
  const unsigned short* csr = g ? csrB : csrA;
  const int* rp = g ? rpB : rpA;
  unsigned short* out = g ? outB : outA;
  const int ldc = g ? ldB : ldA;
  const int co = g ? coB : coA;
  const int lane = threadIdx.x & 63;
  const int grp = lane >> 4;
  const int u = lane & 15;

  float acc[8];
#pragma unroll
  for (int j = 0; j < 8; j++) acc[j] = 0.f;

  int e = rp[v];
  const int end = rp[v + 1];
  for (; e + 8 <= end; e += 8) {
    int s0 = csr[e + grp];
    int s1 = csr[e + 4 + grp];
    uint4 m0 = *(const uint4*)(hs + (size_t)s0 * 128 + u * 8);
    uint4 m1 = *(const uint4*)(hs + (size_t)s1 * 128 + u * 8);
    ACC8(m0);
    ACC8(m1);
  }
  if (e + 4 <= end) {
    int s0 = csr[e + grp];
    uint4 m0 = *(const uint4*)(hs + (size_t)s0 * 128 + u * 8);
    ACC8(m0);
    e += 4;
  }
  int r = end - e;  // 0..3
  if (r > 0) {
    int s0 = csr[e + (grp < r ? grp : r - 1)];
    uint4 m = *(const uint4*)(hs + (size_t)s0 * 128 + u * 8);
    float msk = (grp < r) ? 1.f : 0.f;
    acc[0] = fmaf(msk, bflo(m.x), acc[0]); acc[1] = fmaf(msk, bfhi(m.x), acc[1]);
    acc[2] = fmaf(msk, bflo(m.y), acc[2]); acc[3] = fmaf(msk, bfhi(m.y), acc[3]);
    acc[4] = fmaf(msk, bflo(m.z), acc[4]); acc[5] = fmaf(msk, bfhi(m.z), acc[5]);
    acc[6] = fmaf(msk, bflo(m.w), acc[6]); acc[7] = fmaf(msk, bfhi(m.w), acc[7]);
  }

  // reduce the 4 groups -> lanes 0..15
#pragma unroll
  for (int j = 0; j < 8; j++) {
    acc[j] += __shfl_down(acc[j], 32, 64);
    acc[j] += __shfl_down(acc[j], 16, 64);
  }
  if (grp == 0) {
    uint4 sm = *(const uint4*)(hs + (size_t)v * 128 + u * 8);  // self-loop
    ACC8(sm);
    float dv = dinv[g * N + v];
    float4 b0 = *(const float4*)(bias + u * 8);
    float4 b1 = *(const float4*)(bias + u * 8 + 4);
    float o0 = fmaxf(acc[0] * dv + b0.x, 0.f), o1 = fmaxf(acc[1] * dv + b0.y, 0.f);
    float o2 = fmaxf(acc[2] * dv + b0.z, 0.f), o3 = fmaxf(acc[3] * dv + b0.w, 0.f);
    float o4 = fmaxf(acc[4] * dv + b1.x, 0.f), o5 = fmaxf(acc[5] * dv + b1.y, 0.f);
    float o6 = fmaxf(acc[6] * dv + b1.z, 0.f), o7 = fmaxf(acc[7] * dv + b1.w, 0.f);
    uint4 P;
    P.x = (unsigned)f2bf(o0) | ((unsigned)f2bf(o1) << 16);
    P.y = (unsigned)f2bf(o2) | ((unsigned)f2bf(o3) << 16);
    P.z = (unsigned)f2bf(o4) | ((unsigned)f2bf(o5) << 16);
    P.w = (unsigned)f2bf(o6) | ((unsigned)f2bf(o7) << 16);
    *(uint4*)(out + (size_t)v * ldc + co + u * 8) = P;
  }
}

__launch_bounds__(256)
__global__ void final_out(const float* __restrict__ f, const float* __restrict__ outW,
                          const float* __restrict__ outb, float* __restrict__ y, int n) {
  int gw = (blockIdx.x * 256 + threadIdx.x) >> 6;
  int lane = threadIdx.x & 63;
  if (gw >= n) return;
  const float2* fr = (const float2*)(f + (size_t)gw * 128);
  const float2* w2 = (const float2*)outW;
  float2 a = fr[lane], b = w2[lane];
  float p = a.x * b.x + a.y * b.y;
#pragma unroll
  for (int off = 32; off > 0; off >>= 1) p += __shfl_down(p, off, 64);
  if (lane == 0) y[gw] = 1.f / (1.f + expf(-(p + outb[0])));
}

extern "C" void kernel_launch(void* const* d_in, const int* in_sizes, int n_in,
                              void* d_out, int out_size, void* d_ws, size_t ws_size,
                              hipStream_t stream) {
  const float* meta_a = (const float*)d_in[0];
  const float* meta_b = (const float*)d_in[1];
  const float* x_a    = (const float*)d_in[2];
  const float* x_b    = (const float*)d_in[3];
  const int*   ei_a   = (const int*)d_in[4];
  const int*   ei_b   = (const int*)d_in[5];
  const float* fc1_W = (const float*)d_in[6];
  const float* fc1_b = (const float*)d_in[7];
  const float* fc2_W = (const float*)d_in[8];
  const float* fc2_b = (const float*)d_in[9];
  const float* gcn1_W = (const float*)d_in[10];
  const float* gcn1_b = (const float*)d_in[11];
  const float* gcn2_W = (const float*)d_in[12];
  const float* gcn2_b = (const float*)d_in[13];
  const float* fcc_W = (const float*)d_in[14];
  const float* fcc_b = (const float*)d_in[15];
  const float* out_W = (const float*)d_in[16];
  const float* out_b = (const float*)d_in[17];
  float* y = (float*)d_out;

  const int N = in_sizes[0] / 512;
  const int E = in_sizes[4] / 2;
  const int NB = (N + 511) >> 9;           // <=128 required (N=50000 -> 98)
  const int T = (E + 4095) / 4096;

  char* p = (char*)d_ws;
  auto alloc = [&](size_t bytes) { char* r = p; p += (bytes + 255) & ~255ull; return r; };
  unsigned short* combined = (unsigned short*)alloc((size_t)N * 512 * 2);
  unsigned short* t0 = (unsigned short*)alloc((size_t)N * 128 * 2);
  unsigned short* t1 = (unsigned short*)alloc((size_t)N * 128 * 2);
  unsigned short* t2 = (unsigned short*)alloc((size_t)N * 128 * 2);
  unsigned short* t3 = (unsigned short*)alloc((size_t)N * 128 * 2);
  unsigned short* wt = (unsigned short*)alloc(196608 * 2);
  float* dinv = (float*)alloc((size_t)2 * N * 4);
  int* rpA = (int*)alloc((size_t)(N + 1) * 4);
  int* rpB = (int*)alloc((size_t)(N + 1) * 4);
  int* bucket_cnt = (int*)alloc((size_t)2 * NB * 4);
  int* bbase = (int*)alloc((size_t)2 * (NB + 1) * 4);
  int* gcur = (int*)alloc((size_t)2 * NB * 4);
  size_t rec_bytes = ((size_t)2 * E * 4 + 255) & ~255ull;
  size_t csr_bytes = ((size_t)E * 2 + 255) & ~255ull;
  size_t big_bytes = rec_bytes + 2 * csr_bytes;
  size_t fcc_bytes = (size_t)N * 128 * 4;
  char* big = alloc(big_bytes > fcc_bytes ? big_bytes : fcc_bytes);
  unsigned* records = (unsigned*)big;
  unsigned short* csrA = (unsigned short*)(big + rec_bytes);
  unsigned short* csrB = (unsigned short*)(big + rec_bytes + csr_bytes);
  float* fccout = (float*)big;  // aliases records/csr (dead by head stage)

  unsigned short* wt_fc1 = wt;
  unsigned short* wt_fc2 = wt + 65536;
  unsigned short* wt_g1  = wt + 81920;
  unsigned short* wt_g2  = wt + 114688;
  unsigned short* wt_fcc = wt + 131072;

  const int gemm_grid = (N + GM - 1) / GM;

  prep_w<<<32, 256, 0, stream>>>(fc1_W, fc2_W, gcn1_W, gcn2_W, fcc_W, wt);
  hipMemsetAsync(bucket_cnt, 0, (size_t)2 * NB * 4, stream);
  bucket_hist<<<2 * T, 256, 0, stream>>>(ei_a, ei_b, E, T, NB, bucket_cnt);
  scan_buckets<<<1, 256, 0, stream>>>(bucket_cnt, E, N, NB, bbase, gcur, rpA, rpB);
  bucket_scatter<<<2 * T, 256, 0, stream>>>(ei_a, ei_b, E, T, NB, gcur, records);
  csr_build<<<2 * NB, 256, 0, stream>>>(records, bbase, E, N, NB, rpA, rpB, dinv, csrA, csrB);

  // MLP branches -> combined cols [0,128) and [128,256)
  gemm_mfma<<<gemm_grid, 256, 0, stream>>>(meta_a, 512, 1, wt_fc1, fc1_b, nullptr, t0, nullptr, 128, 0, N, 512, 1);
  gemm_mfma<<<gemm_grid, 256, 0, stream>>>(t0, 128, 0, wt_fc2, fc2_b, nullptr, combined, nullptr, 512, 0, N, 128, 1);
  gemm_mfma<<<gemm_grid, 256, 0, stream>>>(meta_b, 512, 1, wt_fc1, fc1_b, nullptr, t0, nullptr, 128, 0, N, 512, 1);
  gemm_mfma<<<gemm_grid, 256, 0, stream>>>(t0, 128, 0, wt_fc2, fc2_b, nullptr, combined, nullptr, 512, 128, N, 128, 1);

  // GCN layer 1 (both graphs)
  gemm_mfma<<<gemm_grid, 256, 0, stream>>>(x_a, 256, 1, wt_g1, nullptr, dinv,     t0, nullptr, 128, 0, N, 256, 0);
  gemm_mfma<<<gemm_grid, 256, 0, stream>>>(x_b, 256, 1, wt_g1, nullptr, dinv + N, t1, nullptr, 128, 0, N, 256, 0);
  gather4<<<(2 * N + 3) / 4, 256, 0, stream>>>(t0, t1, csrA, csrB, rpA, rpB, dinv, gcn1_b,
                                               t2, t3, 128, 0, 128, 0, N);
  // GCN layer 2 -> combined cols [256,384) and [384,512)
  gemm_mfma<<<gemm_grid, 256, 0, stream>>>(t2, 128, 0, wt_g2, nullptr, dinv,     t0, nullptr, 128, 0, N, 128, 0);
  gemm_mfma<<<gemm_grid, 256, 0, stream>>>(t3, 128, 0, wt_g2, nullptr, dinv + N, t1, nullptr, 128, 0, N, 128, 0);
  gather4<<<(2 * N + 3) / 4, 256, 0, stream>>>(t0, t1, csrA, csrB, rpA, rpB, dinv, gcn2_b,
                                               combined, combined, 512, 256, 512, 384, N);

  // head
  gemm_mfma<<<gemm_grid, 256, 0, stream>>>(combined, 512, 0, wt_fcc, fcc_b, nullptr, nullptr, fccout, 128, 0, N, 512, 1);
  final_out<<<(N + 3) / 4, 256, 0, stream>>>(fccout, out_W, out_b, y, N);
}